// Round 3
// baseline (373.460 us; speedup 1.0000x reference)
//
#include <hip/hip_runtime.h>
#include <hip/hip_fp16.h>

#define NN 100000
#define NE 1600000
#define DD 32
#define NL 3
#define NK 3

#define BK 512                       // nodes per bucket
#define NBK ((NN + BK - 1) / BK)     // 196 buckets
#define EA 4096                      // edges per count/scatter block
#define GA ((NE + EA - 1) / EA)      // 391 blocks
#define NCNT (NBK * GA)              // 76636 count-matrix entries
#define NSC ((NCNT + 255) / 256)     // 300 scan blocks
#define CB (NN * DD / 4 / 256)       // 3125 cvt rider blocks (float4)

typedef _Float16 half8 __attribute__((ext_vector_type(8)));
typedef float f32x4 __attribute__((ext_vector_type(4)));

// ---- pass A: per-(block,bucket) edge counts via LDS atomics (no global atomics);
//      cvt (x->fp16) and W-prep ride as extra blocks. ----
__global__ void countA_kernel(const int* __restrict__ col, unsigned* __restrict__ cntAB,
                              const float* __restrict__ x, __half* __restrict__ xh,
                              const float* __restrict__ W, half8* __restrict__ Bpk) {
    __shared__ unsigned hc[NBK];
    int bid = blockIdx.x;
    int t = threadIdx.x;
    if (bid < GA) {
        for (int i = t; i < NBK; i += 256) hc[i] = 0;
        __syncthreads();
        int e0 = bid * EA;
        int e1 = e0 + EA; if (e1 > NE) e1 = NE;
        for (int e = e0 + t; e < e1; e += 256)
            atomicAdd(&hc[((unsigned)col[e]) >> 9], 1u);
        __syncthreads();
        for (int i = t; i < NBK; i += 256)
            cntAB[i * GA + bid] = hc[i];            // bucket-major for the scan
    } else if (bid < GA + CB) {
        int i = (bid - GA) * 256 + t;               // float4 index, 800000 total
        f32x4 v = ((const f32x4*)x)[i];
        __half2 h01 = __floats2half2_rn(v.x, v.y);
        __half2 h23 = __floats2half2_rn(v.z, v.w);
        int2 o;
        o.x = *(int*)&h01; o.y = *(int*)&h23;
        ((int2*)xh)[i] = o;
    } else if (t < 64) {
        // pre-pack B fragments (hi/lo fp16 split, lane layout) for one layer
        int l = bid - GA - CB;
        int m = t & 15, kq = t >> 4;
        for (int c = 0; c < 4; ++c) {
            for (int h = 0; h < 2; ++h) {
                half8 hi, lo;
                for (int j = 0; j < 8; ++j) {
                    float wv = W[(size_t)((l * 4 + c) * DD + kq * 8 + j) * DD + h * 16 + m];
                    _Float16 wh = (_Float16)wv;
                    hi[j] = wh;
                    lo[j] = (_Float16)(wv - (float)wh);
                }
                Bpk[(size_t)(((l * 4 + c) * 2 + h) * 2 + 0) * 64 + t] = hi;
                Bpk[(size_t)(((l * 4 + c) * 2 + h) * 2 + 1) * 64 + t] = lo;
            }
        }
    }
}

// ---- pass B: 3-level exclusive scan of cntAB (76636 entries) ----
__global__ void scanb_kernel(unsigned* __restrict__ a, unsigned* __restrict__ bsum) {
    __shared__ unsigned s[256];
    int t = threadIdx.x;
    int i = blockIdx.x * 256 + t;
    unsigned v = (i < NCNT) ? a[i] : 0u;
    s[t] = v;
    __syncthreads();
    for (int off = 1; off < 256; off <<= 1) {
        unsigned add = (t >= off) ? s[t - off] : 0u;
        __syncthreads();
        s[t] += add;
        __syncthreads();
    }
    if (i < NCNT) a[i] = s[t] - v;                  // block-local exclusive
    if (t == 255) bsum[blockIdx.x] = s[255];
}

__global__ void scant_kernel(unsigned* __restrict__ bsum) {
    __shared__ unsigned s[512];
    int t = threadIdx.x;
    unsigned v = (t < NSC) ? bsum[t] : 0u;
    s[t] = v;
    __syncthreads();
    for (int off = 1; off < 512; off <<= 1) {
        unsigned add = (t >= off) ? s[t - off] : 0u;
        __syncthreads();
        s[t] += add;
        __syncthreads();
    }
    if (t < NSC) bsum[t] = s[t] - v;                // exclusive block offsets
}

__global__ void scana_kernel(unsigned* __restrict__ a, const unsigned* __restrict__ bsum,
                             unsigned* __restrict__ bbase) {
    int i = blockIdx.x * 256 + threadIdx.x;
    if (i < NCNT) {
        unsigned v = a[i] + bsum[i >> 8];
        a[i] = v;
        if (i % GA == 0) bbase[i / GA] = v;         // bucket base = scan at bucket start
    }
    if (i == 0) bbase[NBK] = NE;
}

// ---- pass C: scatter (colLow<<17|row, w) records bucket-contiguously; LDS cursors ----
__global__ void scatterC_kernel(const int* __restrict__ row, const int* __restrict__ col,
                                const float* __restrict__ w,
                                const unsigned* __restrict__ cntAB, int2* __restrict__ eb) {
    __shared__ unsigned cur[NBK];
    int bid = blockIdx.x;
    int t = threadIdx.x;
    for (int i = t; i < NBK; i += 256) cur[i] = cntAB[i * GA + bid];
    __syncthreads();
    int e0 = bid * EA;
    int e1 = e0 + EA; if (e1 > NE) e1 = NE;
    for (int e = e0 + t; e < e1; e += 256) {
        unsigned c = (unsigned)col[e];
        unsigned pos = atomicAdd(&cur[c >> 9], 1u);
        eb[pos] = make_int2((int)(((c & 511u) << 17) | (unsigned)row[e]),
                            __float_as_int(w[e]));
    }
}

// ---- pass D1: per-bucket node histogram (packed count|wsum fixed 2^-17) -> ptr, dis ----
__global__ void histD1_kernel(const int2* __restrict__ eb, const unsigned* __restrict__ bbase,
                              int* __restrict__ ptr, float* __restrict__ dis) {
    __shared__ unsigned h[BK];
    __shared__ unsigned ps[256];
    int b = blockIdx.x;
    int t = threadIdx.x;
    h[t] = 0; h[t + 256] = 0;
    __syncthreads();
    unsigned e0 = bbase[b], e1 = bbase[b + 1];
    for (unsigned e = e0 + t; e < e1; e += 256) {
        int2 E = eb[e];
        unsigned cl = ((unsigned)E.x) >> 17;
        float wv = __int_as_float(E.y);
        atomicAdd(&h[cl], (1u << 24) | (unsigned)(wv * 131072.0f));
    }
    __syncthreads();
    unsigned c0 = h[2 * t] >> 24, c1 = h[2 * t + 1] >> 24;
    unsigned pv = c0 + c1;
    ps[t] = pv;
    __syncthreads();
    for (int off = 1; off < 256; off <<= 1) {
        unsigned add = (t >= off) ? ps[t - off] : 0u;
        __syncthreads();
        ps[t] += add;
        __syncthreads();
    }
    unsigned base = e0 + ps[t] - pv;                // exclusive pair prefix
    int n0 = b * BK + 2 * t;
    if (n0 < NN) {
        ptr[n0] = (int)base;
        float dg = (float)(h[2 * t] & 0xFFFFFFu) * (1.0f / 131072.0f);
        dis[n0] = dg > 0.f ? rsqrtf(dg) : 0.f;
    }
    if (n0 + 1 < NN) {
        ptr[n0 + 1] = (int)(base + c0);
        float dg = (float)(h[2 * t + 1] & 0xFFFFFFu) * (1.0f / 131072.0f);
        dis[n0 + 1] = dg > 0.f ? rsqrtf(dg) : 0.f;
    }
    if (b == 0 && t == 0) ptr[NN] = NE;
}

// ---- pass D2: per-bucket CSR fill via LDS cursors: epair = (fp16(norm)<<17)|row ----
__global__ void fillD2_kernel(const int2* __restrict__ eb, const unsigned* __restrict__ bbase,
                              const int* __restrict__ ptr, const float* __restrict__ dis,
                              unsigned* __restrict__ epair) {
    __shared__ unsigned cur[BK];
    __shared__ float dl[BK];
    int b = blockIdx.x;
    int t = threadIdx.x;
    int n0 = b * BK;
    for (int i = t; i < BK; i += 256) {
        int n = n0 + i;
        cur[i] = (n < NN) ? (unsigned)ptr[n] : 0u;
        dl[i] = (n < NN) ? dis[n] : 0.f;
    }
    __syncthreads();
    unsigned e0 = bbase[b], e1 = bbase[b + 1];
    for (unsigned e = e0 + t; e < e1; e += 256) {
        int2 E = eb[e];
        unsigned cl = ((unsigned)E.x) >> 17;
        unsigned r = ((unsigned)E.x) & 0x1FFFFu;
        float nv = dis[r] * __int_as_float(E.y) * dl[cl];
        unsigned pos = atomicAdd(&cur[cl], 1u);
        unsigned hb = (unsigned)__half_as_ushort(__float2half(nv));
        epair[pos] = (hb << 17) | r;
    }
}

// ---- gather body, 16 lanes/node, NO shuffles on the critical path:
//      lane (st,c4) walks edges e = p0+st, p0+st+4, ... loading epair[e] directly
//      (4 lanes of a c4-quartet broadcast-read the same word; quartets are
//      consecutive -> stream stays coalesced). 2-deep software pipeline keeps
//      two independent 64B row-fetches in flight per node. ----
__device__ __forceinline__ void gather_body16(const ushort* __restrict__ hin,
                                              const unsigned* __restrict__ epair,
                                              int p0, int p1, int st, int c4,
                                              float agg[8]) {
    const int4* hin4 = (const int4*)hin;
    int e = p0 + st;
    if (e < p1) {
        unsigned pc = __builtin_nontemporal_load(epair + e);
        int4 rw = hin4[(size_t)(pc & 0x1FFFFu) * 4 + c4];
        e += 4;
        while (e < p1) {
            unsigned pn = __builtin_nontemporal_load(epair + e);
            int4 rn = hin4[(size_t)(pn & 0x1FFFFu) * 4 + c4];
            float vv = __half2float(__ushort_as_half((unsigned short)(pc >> 17)));
            float2 f0 = __half22float2(*reinterpret_cast<__half2*>(&rw.x));
            float2 f1 = __half22float2(*reinterpret_cast<__half2*>(&rw.y));
            float2 f2 = __half22float2(*reinterpret_cast<__half2*>(&rw.z));
            float2 f3 = __half22float2(*reinterpret_cast<__half2*>(&rw.w));
            agg[0] = fmaf(vv, f0.x, agg[0]); agg[1] = fmaf(vv, f0.y, agg[1]);
            agg[2] = fmaf(vv, f1.x, agg[2]); agg[3] = fmaf(vv, f1.y, agg[3]);
            agg[4] = fmaf(vv, f2.x, agg[4]); agg[5] = fmaf(vv, f2.y, agg[5]);
            agg[6] = fmaf(vv, f3.x, agg[6]); agg[7] = fmaf(vv, f3.y, agg[7]);
            pc = pn; rw = rn;
            e += 4;
        }
        float vv = __half2float(__ushort_as_half((unsigned short)(pc >> 17)));
        float2 f0 = __half22float2(*reinterpret_cast<__half2*>(&rw.x));
        float2 f1 = __half22float2(*reinterpret_cast<__half2*>(&rw.y));
        float2 f2 = __half22float2(*reinterpret_cast<__half2*>(&rw.z));
        float2 f3 = __half22float2(*reinterpret_cast<__half2*>(&rw.w));
        agg[0] = fmaf(vv, f0.x, agg[0]); agg[1] = fmaf(vv, f0.y, agg[1]);
        agg[2] = fmaf(vv, f1.x, agg[2]); agg[3] = fmaf(vv, f1.y, agg[3]);
        agg[4] = fmaf(vv, f2.x, agg[4]); agg[5] = fmaf(vv, f2.y, agg[5]);
        agg[6] = fmaf(vv, f3.x, agg[6]); agg[7] = fmaf(vv, f3.y, agg[7]);
    }
    // reduce over the 4 streams (st) within each 16-lane group
    #pragma unroll
    for (int i = 0; i < 8; ++i) {
        agg[i] += __shfl_xor(agg[i], 4, 16);
        agg[i] += __shfl_xor(agg[i], 8, 16);
    }
}

// --- pure hop: hout[n] = sum norm*hin[src], fp16 in/out. 256 thr = 16 nodes ---
__global__ __launch_bounds__(256) void gather_kernel(
    const ushort* __restrict__ hin, ushort* __restrict__ hout,
    const int* __restrict__ ptr, const unsigned* __restrict__ epair) {
    int tid = threadIdx.x;
    int lane16 = tid & 15;
    int st = lane16 >> 2, c4 = lane16 & 3;
    int n = blockIdx.x * 16 + (tid >> 4);      // NN = 6250*16 exactly
    int p0 = ptr[n], p1 = ptr[n + 1];
    float agg[8] = {0.f, 0.f, 0.f, 0.f, 0.f, 0.f, 0.f, 0.f};
    gather_body16(hin, epair, p0, p1, st, c4, agg);
    if (lane16 < 4) {
        __half2 ha = __floats2half2_rn(agg[0], agg[1]);
        __half2 hb = __floats2half2_rn(agg[2], agg[3]);
        __half2 hc = __floats2half2_rn(agg[4], agg[5]);
        __half2 hd = __floats2half2_rn(agg[6], agg[7]);
        int4 pkv;
        pkv.x = *(int*)&ha; pkv.y = *(int*)&hb;
        pkv.z = *(int*)&hc; pkv.w = *(int*)&hd;
        ((int4*)hout)[(size_t)n * 4 + lane16] = pkv;
    }
}

// --- fused k=3 gather + MFMA epilogue. 256 threads = 16 nodes (16 lanes/node) ---
__global__ __launch_bounds__(256) void k3ep_kernel(
    const ushort* __restrict__ f0, const ushort* __restrict__ h1,
    const ushort* __restrict__ h2,
    ushort* __restrict__ f0out, float* __restrict__ outf,
    const int* __restrict__ ptr, const unsigned* __restrict__ epair,
    const half8* __restrict__ Bp, const float* __restrict__ bias, int last) {
    __shared__ __half ldsH[16 * DD];
    int tid = threadIdx.x;
    int lane16 = tid & 15;
    int st = lane16 >> 2, c4 = lane16 & 3;
    int nloc = tid >> 4;                 // 0..15
    int n0 = blockIdx.x * 16;
    int n = n0 + nloc;                   // NN = 6250*16 exactly, no guard needed
    int p0 = ptr[n], p1 = ptr[n + 1];
    float agg[8] = {0.f, 0.f, 0.f, 0.f, 0.f, 0.f, 0.f, 0.f};
    gather_body16(h2, epair, p0, p1, st, c4, agg);
    if (lane16 < 4) {
        __half2 ha = __floats2half2_rn(agg[0], agg[1]);
        __half2 hb = __floats2half2_rn(agg[2], agg[3]);
        __half2 hc = __floats2half2_rn(agg[4], agg[5]);
        __half2 hd = __floats2half2_rn(agg[6], agg[7]);
        int4 pkv;
        pkv.x = *(int*)&ha; pkv.y = *(int*)&hb;
        pkv.z = *(int*)&hc; pkv.w = *(int*)&hd;
        *(int4*)&ldsH[nloc * DD + lane16 * 8] = pkv;
    }
    __syncthreads();
    if (tid < 64) {
        int m = tid & 15, kq = tid >> 4;
        int ai = (n0 + m) * 4 + kq;
        const half8* A0 = (const half8*)f0;
        const half8* A1 = (const half8*)h1;
        const half8* A2 = (const half8*)h2;
        f32x4 acc0 = {0.f, 0.f, 0.f, 0.f};
        f32x4 acc1 = {0.f, 0.f, 0.f, 0.f};
        half8 a;
        a = A0[ai];
        acc0 = __builtin_amdgcn_mfma_f32_16x16x32_f16(a, Bp[0 * 64 + tid], acc0, 0, 0, 0);
        acc0 = __builtin_amdgcn_mfma_f32_16x16x32_f16(a, Bp[1 * 64 + tid], acc0, 0, 0, 0);
        acc1 = __builtin_amdgcn_mfma_f32_16x16x32_f16(a, Bp[2 * 64 + tid], acc1, 0, 0, 0);
        acc1 = __builtin_amdgcn_mfma_f32_16x16x32_f16(a, Bp[3 * 64 + tid], acc1, 0, 0, 0);
        a = A1[ai];
        acc0 = __builtin_amdgcn_mfma_f32_16x16x32_f16(a, Bp[4 * 64 + tid], acc0, 0, 0, 0);
        acc0 = __builtin_amdgcn_mfma_f32_16x16x32_f16(a, Bp[5 * 64 + tid], acc0, 0, 0, 0);
        acc1 = __builtin_amdgcn_mfma_f32_16x16x32_f16(a, Bp[6 * 64 + tid], acc1, 0, 0, 0);
        acc1 = __builtin_amdgcn_mfma_f32_16x16x32_f16(a, Bp[7 * 64 + tid], acc1, 0, 0, 0);
        a = A2[ai];
        acc0 = __builtin_amdgcn_mfma_f32_16x16x32_f16(a, Bp[8 * 64 + tid], acc0, 0, 0, 0);
        acc0 = __builtin_amdgcn_mfma_f32_16x16x32_f16(a, Bp[9 * 64 + tid], acc0, 0, 0, 0);
        acc1 = __builtin_amdgcn_mfma_f32_16x16x32_f16(a, Bp[10 * 64 + tid], acc1, 0, 0, 0);
        acc1 = __builtin_amdgcn_mfma_f32_16x16x32_f16(a, Bp[11 * 64 + tid], acc1, 0, 0, 0);
        a = *(const half8*)&ldsH[m * DD + kq * 8];
        acc0 = __builtin_amdgcn_mfma_f32_16x16x32_f16(a, Bp[12 * 64 + tid], acc0, 0, 0, 0);
        acc0 = __builtin_amdgcn_mfma_f32_16x16x32_f16(a, Bp[13 * 64 + tid], acc0, 0, 0, 0);
        acc1 = __builtin_amdgcn_mfma_f32_16x16x32_f16(a, Bp[14 * 64 + tid], acc1, 0, 0, 0);
        acc1 = __builtin_amdgcn_mfma_f32_16x16x32_f16(a, Bp[15 * 64 + tid], acc1, 0, 0, 0);
        float b0 = bias[m], b1 = bias[16 + m];
        #pragma unroll
        for (int r = 0; r < 4; ++r) {
            int rowi = n0 + kq * 4 + r;
            float v0 = fmaxf(acc0[r] + b0, 0.f);
            float v1 = fmaxf(acc1[r] + b1, 0.f);
            if (last) {
                outf[rowi * DD + m] = v0;
                outf[rowi * DD + 16 + m] = v1;
            } else {
                ((__half*)f0out)[rowi * DD + m] = __float2half(v0);
                ((__half*)f0out)[rowi * DD + 16 + m] = __float2half(v1);
            }
        }
    }
}

extern "C" void kernel_launch(void* const* d_in, const int* in_sizes, int n_in,
                              void* d_out, int out_size, void* d_ws, size_t ws_size,
                              hipStream_t stream) {
    const float* x  = (const float*)d_in[0];
    const int*   ei = (const int*)d_in[1];
    const float* ew = (const float*)d_in[2];
    const float* W  = (const float*)d_in[3];
    const float* b  = (const float*)d_in[4];
    float* out = (float*)d_out;

    const int* row = ei;        // source
    const int* col = ei + NE;   // target

    // ws layout (bytes), ~26.8 MB. eb is dead after fillD2 -> h1/h2 alias it.
    // eb 12.8M (h1 @0, h2 @6.4M) | epair 6.4M | f0 6.4M | ptr 400016 |
    // dis 400000 | cntAB 306544 | bsum 1216 | bbase 800 | Bpk 49152
    char* base = (char*)d_ws;
    int2*     eb    = (int2*)base;
    ushort*   h1    = (ushort*)base;
    ushort*   h2    = (ushort*)(base + 6400000);
    unsigned* epair = (unsigned*)(base + 12800000);
    ushort*   f0    = (ushort*)(base + 19200000);
    int*      ptr   = (int*)(base + 25600000);
    float*    dis   = (float*)(base + 26000016);
    unsigned* cntAB = (unsigned*)(base + 26400016);
    unsigned* bsum  = (unsigned*)(base + 26706560);
    unsigned* bbase = (unsigned*)(base + 26707776);
    half8*    Bpk   = (half8*)(base + 26708576);

    // ---- bucket-radix CSR build (no global atomics); cvt + prep ride in pass A ----
    countA_kernel<<<GA + CB + NL, 256, 0, stream>>>(col, cntAB, x, (__half*)f0, W, Bpk);
    scanb_kernel<<<NSC, 256, 0, stream>>>(cntAB, bsum);
    scant_kernel<<<1, 512, 0, stream>>>(bsum);
    scana_kernel<<<NSC, 256, 0, stream>>>(cntAB, bsum, bbase);
    scatterC_kernel<<<GA, 256, 0, stream>>>(row, col, ew, cntAB, eb);
    histD1_kernel<<<NBK, 256, 0, stream>>>(eb, bbase, ptr, dis);
    fillD2_kernel<<<NBK, 256, 0, stream>>>(eb, bbase, ptr, dis, epair);

    // ---- layers: f0 = layer input (fp16, updated in place by fused epilogue) ----
    const int grid = NN / 16;
    for (int l = 0; l < NL; ++l) {
        int lastl = (l == NL - 1);
        gather_kernel<<<grid, 256, 0, stream>>>(f0, h1, ptr, epair);   // k=1
        gather_kernel<<<grid, 256, 0, stream>>>(h1, h2, ptr, epair);   // k=2
        k3ep_kernel<<<grid, 256, 0, stream>>>(f0, h1, h2, f0, out, ptr, epair,
                                              Bpk + (size_t)l * 1024,
                                              b + (size_t)l * DD, lastl);
    }
}

// Round 4
// 316.873 us; speedup vs baseline: 1.1786x; 1.1786x over previous
//
#include <hip/hip_runtime.h>
#include <hip/hip_fp16.h>

#define NN 100000
#define NE 1600000
#define DD 32
#define NL 3
#define NK 3

#define BK 512                       // nodes per bucket
#define NBK ((NN + BK - 1) / BK)     // 196 buckets
#define EA 4096                      // edges per count/scatter block
#define GA ((NE + EA - 1) / EA)      // 391 blocks
#define NCNT (NBK * GA)              // 76636 count-matrix entries
#define NSC ((NCNT + 255) / 256)     // 300 scan blocks
#define CB (NN * DD / 4 / 256)       // 3125 cvt rider blocks (float4)

typedef _Float16 half8 __attribute__((ext_vector_type(8)));
typedef float f32x4 __attribute__((ext_vector_type(4)));

// ---- pass A: per-(block,bucket) edge counts via LDS atomics (no global atomics);
//      cvt (x->fp16) and W-prep ride as extra blocks. ----
__global__ void countA_kernel(const int* __restrict__ col, unsigned* __restrict__ cntAB,
                              const float* __restrict__ x, __half* __restrict__ xh,
                              const float* __restrict__ W, half8* __restrict__ Bpk) {
    __shared__ unsigned hc[NBK];
    int bid = blockIdx.x;
    int t = threadIdx.x;
    if (bid < GA) {
        for (int i = t; i < NBK; i += 256) hc[i] = 0;
        __syncthreads();
        int e0 = bid * EA;
        int e1 = e0 + EA; if (e1 > NE) e1 = NE;
        for (int e = e0 + t; e < e1; e += 256)
            atomicAdd(&hc[((unsigned)col[e]) >> 9], 1u);
        __syncthreads();
        for (int i = t; i < NBK; i += 256)
            cntAB[i * GA + bid] = hc[i];            // bucket-major for the scan
    } else if (bid < GA + CB) {
        int i = (bid - GA) * 256 + t;               // float4 index, 800000 total
        f32x4 v = ((const f32x4*)x)[i];
        __half2 h01 = __floats2half2_rn(v.x, v.y);
        __half2 h23 = __floats2half2_rn(v.z, v.w);
        int2 o;
        o.x = *(int*)&h01; o.y = *(int*)&h23;
        ((int2*)xh)[i] = o;
    } else if (t < 64) {
        // pre-pack B fragments (hi/lo fp16 split, lane layout) for one layer
        int l = bid - GA - CB;
        int m = t & 15, kq = t >> 4;
        for (int c = 0; c < 4; ++c) {
            for (int h = 0; h < 2; ++h) {
                half8 hi, lo;
                for (int j = 0; j < 8; ++j) {
                    float wv = W[(size_t)((l * 4 + c) * DD + kq * 8 + j) * DD + h * 16 + m];
                    _Float16 wh = (_Float16)wv;
                    hi[j] = wh;
                    lo[j] = (_Float16)(wv - (float)wh);
                }
                Bpk[(size_t)(((l * 4 + c) * 2 + h) * 2 + 0) * 64 + t] = hi;
                Bpk[(size_t)(((l * 4 + c) * 2 + h) * 2 + 1) * 64 + t] = lo;
            }
        }
    }
}

// ---- pass B: 3-level exclusive scan of cntAB (76636 entries) ----
__global__ void scanb_kernel(unsigned* __restrict__ a, unsigned* __restrict__ bsum) {
    __shared__ unsigned s[256];
    int t = threadIdx.x;
    int i = blockIdx.x * 256 + t;
    unsigned v = (i < NCNT) ? a[i] : 0u;
    s[t] = v;
    __syncthreads();
    for (int off = 1; off < 256; off <<= 1) {
        unsigned add = (t >= off) ? s[t - off] : 0u;
        __syncthreads();
        s[t] += add;
        __syncthreads();
    }
    if (i < NCNT) a[i] = s[t] - v;                  // block-local exclusive
    if (t == 255) bsum[blockIdx.x] = s[255];
}

__global__ void scant_kernel(unsigned* __restrict__ bsum) {
    __shared__ unsigned s[512];
    int t = threadIdx.x;
    unsigned v = (t < NSC) ? bsum[t] : 0u;
    s[t] = v;
    __syncthreads();
    for (int off = 1; off < 512; off <<= 1) {
        unsigned add = (t >= off) ? s[t - off] : 0u;
        __syncthreads();
        s[t] += add;
        __syncthreads();
    }
    if (t < NSC) bsum[t] = s[t] - v;                // exclusive block offsets
}

__global__ void scana_kernel(unsigned* __restrict__ a, const unsigned* __restrict__ bsum,
                             unsigned* __restrict__ bbase) {
    int i = blockIdx.x * 256 + threadIdx.x;
    if (i < NCNT) {
        unsigned v = a[i] + bsum[i >> 8];
        a[i] = v;
        if (i % GA == 0) bbase[i / GA] = v;         // bucket base = scan at bucket start
    }
    if (i == 0) bbase[NBK] = NE;
}

// ---- pass C: scatter (colLow<<17|row, w) records bucket-contiguously; LDS cursors ----
__global__ void scatterC_kernel(const int* __restrict__ row, const int* __restrict__ col,
                                const float* __restrict__ w,
                                const unsigned* __restrict__ cntAB, int2* __restrict__ eb) {
    __shared__ unsigned cur[NBK];
    int bid = blockIdx.x;
    int t = threadIdx.x;
    for (int i = t; i < NBK; i += 256) cur[i] = cntAB[i * GA + bid];
    __syncthreads();
    int e0 = bid * EA;
    int e1 = e0 + EA; if (e1 > NE) e1 = NE;
    for (int e = e0 + t; e < e1; e += 256) {
        unsigned c = (unsigned)col[e];
        unsigned pos = atomicAdd(&cur[c >> 9], 1u);
        eb[pos] = make_int2((int)(((c & 511u) << 17) | (unsigned)row[e]),
                            __float_as_int(w[e]));
    }
}

// ---- pass D1: per-bucket node histogram (packed count|wsum fixed 2^-17) -> ptr, dis ----
__global__ void histD1_kernel(const int2* __restrict__ eb, const unsigned* __restrict__ bbase,
                              int* __restrict__ ptr, float* __restrict__ dis) {
    __shared__ unsigned h[BK];
    __shared__ unsigned ps[256];
    int b = blockIdx.x;
    int t = threadIdx.x;
    h[t] = 0; h[t + 256] = 0;
    __syncthreads();
    unsigned e0 = bbase[b], e1 = bbase[b + 1];
    for (unsigned e = e0 + t; e < e1; e += 256) {
        int2 E = eb[e];
        unsigned cl = ((unsigned)E.x) >> 17;
        float wv = __int_as_float(E.y);
        atomicAdd(&h[cl], (1u << 24) | (unsigned)(wv * 131072.0f));
    }
    __syncthreads();
    unsigned c0 = h[2 * t] >> 24, c1 = h[2 * t + 1] >> 24;
    unsigned pv = c0 + c1;
    ps[t] = pv;
    __syncthreads();
    for (int off = 1; off < 256; off <<= 1) {
        unsigned add = (t >= off) ? ps[t - off] : 0u;
        __syncthreads();
        ps[t] += add;
        __syncthreads();
    }
    unsigned base = e0 + ps[t] - pv;                // exclusive pair prefix
    int n0 = b * BK + 2 * t;
    if (n0 < NN) {
        ptr[n0] = (int)base;
        float dg = (float)(h[2 * t] & 0xFFFFFFu) * (1.0f / 131072.0f);
        dis[n0] = dg > 0.f ? rsqrtf(dg) : 0.f;
    }
    if (n0 + 1 < NN) {
        ptr[n0 + 1] = (int)(base + c0);
        float dg = (float)(h[2 * t + 1] & 0xFFFFFFu) * (1.0f / 131072.0f);
        dis[n0 + 1] = dg > 0.f ? rsqrtf(dg) : 0.f;
    }
    if (b == 0 && t == 0) ptr[NN] = NE;
}

// ---- pass D2: per-bucket CSR fill via LDS cursors: epair = (fp16(norm)<<17)|row ----
__global__ void fillD2_kernel(const int2* __restrict__ eb, const unsigned* __restrict__ bbase,
                              const int* __restrict__ ptr, const float* __restrict__ dis,
                              unsigned* __restrict__ epair) {
    __shared__ unsigned cur[BK];
    __shared__ float dl[BK];
    int b = blockIdx.x;
    int t = threadIdx.x;
    int n0 = b * BK;
    for (int i = t; i < BK; i += 256) {
        int n = n0 + i;
        cur[i] = (n < NN) ? (unsigned)ptr[n] : 0u;
        dl[i] = (n < NN) ? dis[n] : 0.f;
    }
    __syncthreads();
    unsigned e0 = bbase[b], e1 = bbase[b + 1];
    for (unsigned e = e0 + t; e < e1; e += 256) {
        int2 E = eb[e];
        unsigned cl = ((unsigned)E.x) >> 17;
        unsigned r = ((unsigned)E.x) & 0x1FFFFu;
        float nv = dis[r] * __int_as_float(E.y) * dl[cl];
        unsigned pos = atomicAdd(&cur[cl], 1u);
        unsigned hb = (unsigned)__half_as_ushort(__float2half(nv));
        epair[pos] = (hb << 17) | r;
    }
}

// ---- gather body, 16 lanes/node, 4-deep batched rounds:
//      stream lane (st,c4) owns edges p0+st+4d; per round it issues ALL 4 epair
//      loads then ALL 4 independent row loads before any FMA -> 64 cachelines
//      in flight per wave (4 nodes x 16 edges). OOB depths clamp the address
//      (weight forced to 0) so loads stay unconditional and batched. ----
#define ACC8(rw, vv)                                                             \
    {                                                                            \
        float2 f0 = __half22float2(*reinterpret_cast<__half2*>(&rw.x));          \
        float2 f1 = __half22float2(*reinterpret_cast<__half2*>(&rw.y));          \
        float2 f2 = __half22float2(*reinterpret_cast<__half2*>(&rw.z));          \
        float2 f3 = __half22float2(*reinterpret_cast<__half2*>(&rw.w));          \
        agg[0] = fmaf(vv, f0.x, agg[0]); agg[1] = fmaf(vv, f0.y, agg[1]);        \
        agg[2] = fmaf(vv, f1.x, agg[2]); agg[3] = fmaf(vv, f1.y, agg[3]);        \
        agg[4] = fmaf(vv, f2.x, agg[4]); agg[5] = fmaf(vv, f2.y, agg[5]);        \
        agg[6] = fmaf(vv, f3.x, agg[6]); agg[7] = fmaf(vv, f3.y, agg[7]);        \
    }

__device__ __forceinline__ void gather_body16(const ushort* __restrict__ hin,
                                              const unsigned* __restrict__ epair,
                                              int p0, int p1, int st, int c4,
                                              float agg[8]) {
    const int4* hin4 = (const int4*)hin;
    for (int e = p0 + st; e < p1; e += 16) {
        int eA = e;                                  // valid by loop condition
        int eB = (e + 4  < p1) ? e + 4  : p1 - 1;
        int eC = (e + 8  < p1) ? e + 8  : p1 - 1;
        int eD = (e + 12 < p1) ? e + 12 : p1 - 1;
        unsigned pA = epair[eA];
        unsigned pB = epair[eB];
        unsigned pC = epair[eC];
        unsigned pD = epair[eD];
        int4 rA = hin4[(size_t)(pA & 0x1FFFFu) * 4 + c4];
        int4 rB = hin4[(size_t)(pB & 0x1FFFFu) * 4 + c4];
        int4 rC = hin4[(size_t)(pC & 0x1FFFFu) * 4 + c4];
        int4 rD = hin4[(size_t)(pD & 0x1FFFFu) * 4 + c4];
        float vA = __half2float(__ushort_as_half((unsigned short)(pA >> 17)));
        float vB = (e + 4  < p1) ? __half2float(__ushort_as_half((unsigned short)(pB >> 17))) : 0.f;
        float vC = (e + 8  < p1) ? __half2float(__ushort_as_half((unsigned short)(pC >> 17))) : 0.f;
        float vD = (e + 12 < p1) ? __half2float(__ushort_as_half((unsigned short)(pD >> 17))) : 0.f;
        ACC8(rA, vA);
        ACC8(rB, vB);
        ACC8(rC, vC);
        ACC8(rD, vD);
    }
    // reduce over the 4 streams (st) within each 16-lane group
    #pragma unroll
    for (int i = 0; i < 8; ++i) {
        agg[i] += __shfl_xor(agg[i], 4, 16);
        agg[i] += __shfl_xor(agg[i], 8, 16);
    }
}

// --- pure hop: hout[n] = sum norm*hin[src], fp16 in/out. 256 thr = 16 nodes ---
__global__ __launch_bounds__(256) void gather_kernel(
    const ushort* __restrict__ hin, ushort* __restrict__ hout,
    const int* __restrict__ ptr, const unsigned* __restrict__ epair) {
    int tid = threadIdx.x;
    int lane16 = tid & 15;
    int st = lane16 >> 2, c4 = lane16 & 3;
    int n = blockIdx.x * 16 + (tid >> 4);      // NN = 6250*16 exactly
    int p0 = ptr[n], p1 = ptr[n + 1];
    float agg[8] = {0.f, 0.f, 0.f, 0.f, 0.f, 0.f, 0.f, 0.f};
    gather_body16(hin, epair, p0, p1, st, c4, agg);
    if (lane16 < 4) {
        __half2 ha = __floats2half2_rn(agg[0], agg[1]);
        __half2 hb = __floats2half2_rn(agg[2], agg[3]);
        __half2 hc = __floats2half2_rn(agg[4], agg[5]);
        __half2 hd = __floats2half2_rn(agg[6], agg[7]);
        int4 pkv;
        pkv.x = *(int*)&ha; pkv.y = *(int*)&hb;
        pkv.z = *(int*)&hc; pkv.w = *(int*)&hd;
        ((int4*)hout)[(size_t)n * 4 + lane16] = pkv;
    }
}

// --- fused k=3 gather + MFMA epilogue. 256 threads = 16 nodes (16 lanes/node) ---
__global__ __launch_bounds__(256) void k3ep_kernel(
    const ushort* __restrict__ f0, const ushort* __restrict__ h1,
    const ushort* __restrict__ h2,
    ushort* __restrict__ f0out, float* __restrict__ outf,
    const int* __restrict__ ptr, const unsigned* __restrict__ epair,
    const half8* __restrict__ Bp, const float* __restrict__ bias, int last) {
    __shared__ __half ldsH[16 * DD];
    int tid = threadIdx.x;
    int lane16 = tid & 15;
    int st = lane16 >> 2, c4 = lane16 & 3;
    int nloc = tid >> 4;                 // 0..15
    int n0 = blockIdx.x * 16;
    int n = n0 + nloc;                   // NN = 6250*16 exactly, no guard needed
    int p0 = ptr[n], p1 = ptr[n + 1];
    float agg[8] = {0.f, 0.f, 0.f, 0.f, 0.f, 0.f, 0.f, 0.f};
    gather_body16(h2, epair, p0, p1, st, c4, agg);
    if (lane16 < 4) {
        __half2 ha = __floats2half2_rn(agg[0], agg[1]);
        __half2 hb = __floats2half2_rn(agg[2], agg[3]);
        __half2 hc = __floats2half2_rn(agg[4], agg[5]);
        __half2 hd = __floats2half2_rn(agg[6], agg[7]);
        int4 pkv;
        pkv.x = *(int*)&ha; pkv.y = *(int*)&hb;
        pkv.z = *(int*)&hc; pkv.w = *(int*)&hd;
        *(int4*)&ldsH[nloc * DD + lane16 * 8] = pkv;
    }
    __syncthreads();
    if (tid < 64) {
        int m = tid & 15, kq = tid >> 4;
        int ai = (n0 + m) * 4 + kq;
        const half8* A0 = (const half8*)f0;
        const half8* A1 = (const half8*)h1;
        const half8* A2 = (const half8*)h2;
        f32x4 acc0 = {0.f, 0.f, 0.f, 0.f};
        f32x4 acc1 = {0.f, 0.f, 0.f, 0.f};
        half8 a;
        a = A0[ai];
        acc0 = __builtin_amdgcn_mfma_f32_16x16x32_f16(a, Bp[0 * 64 + tid], acc0, 0, 0, 0);
        acc0 = __builtin_amdgcn_mfma_f32_16x16x32_f16(a, Bp[1 * 64 + tid], acc0, 0, 0, 0);
        acc1 = __builtin_amdgcn_mfma_f32_16x16x32_f16(a, Bp[2 * 64 + tid], acc1, 0, 0, 0);
        acc1 = __builtin_amdgcn_mfma_f32_16x16x32_f16(a, Bp[3 * 64 + tid], acc1, 0, 0, 0);
        a = A1[ai];
        acc0 = __builtin_amdgcn_mfma_f32_16x16x32_f16(a, Bp[4 * 64 + tid], acc0, 0, 0, 0);
        acc0 = __builtin_amdgcn_mfma_f32_16x16x32_f16(a, Bp[5 * 64 + tid], acc0, 0, 0, 0);
        acc1 = __builtin_amdgcn_mfma_f32_16x16x32_f16(a, Bp[6 * 64 + tid], acc1, 0, 0, 0);
        acc1 = __builtin_amdgcn_mfma_f32_16x16x32_f16(a, Bp[7 * 64 + tid], acc1, 0, 0, 0);
        a = A2[ai];
        acc0 = __builtin_amdgcn_mfma_f32_16x16x32_f16(a, Bp[8 * 64 + tid], acc0, 0, 0, 0);
        acc0 = __builtin_amdgcn_mfma_f32_16x16x32_f16(a, Bp[9 * 64 + tid], acc0, 0, 0, 0);
        acc1 = __builtin_amdgcn_mfma_f32_16x16x32_f16(a, Bp[10 * 64 + tid], acc1, 0, 0, 0);
        acc1 = __builtin_amdgcn_mfma_f32_16x16x32_f16(a, Bp[11 * 64 + tid], acc1, 0, 0, 0);
        a = *(const half8*)&ldsH[m * DD + kq * 8];
        acc0 = __builtin_amdgcn_mfma_f32_16x16x32_f16(a, Bp[12 * 64 + tid], acc0, 0, 0, 0);
        acc0 = __builtin_amdgcn_mfma_f32_16x16x32_f16(a, Bp[13 * 64 + tid], acc0, 0, 0, 0);
        acc1 = __builtin_amdgcn_mfma_f32_16x16x32_f16(a, Bp[14 * 64 + tid], acc1, 0, 0, 0);
        acc1 = __builtin_amdgcn_mfma_f32_16x16x32_f16(a, Bp[15 * 64 + tid], acc1, 0, 0, 0);
        float b0 = bias[m], b1 = bias[16 + m];
        #pragma unroll
        for (int r = 0; r < 4; ++r) {
            int rowi = n0 + kq * 4 + r;
            float v0 = fmaxf(acc0[r] + b0, 0.f);
            float v1 = fmaxf(acc1[r] + b1, 0.f);
            if (last) {
                outf[rowi * DD + m] = v0;
                outf[rowi * DD + 16 + m] = v1;
            } else {
                ((__half*)f0out)[rowi * DD + m] = __float2half(v0);
                ((__half*)f0out)[rowi * DD + 16 + m] = __float2half(v1);
            }
        }
    }
}

extern "C" void kernel_launch(void* const* d_in, const int* in_sizes, int n_in,
                              void* d_out, int out_size, void* d_ws, size_t ws_size,
                              hipStream_t stream) {
    const float* x  = (const float*)d_in[0];
    const int*   ei = (const int*)d_in[1];
    const float* ew = (const float*)d_in[2];
    const float* W  = (const float*)d_in[3];
    const float* b  = (const float*)d_in[4];
    float* out = (float*)d_out;

    const int* row = ei;        // source
    const int* col = ei + NE;   // target

    // ws layout (bytes), ~26.8 MB. eb is dead after fillD2 -> h1/h2 alias it.
    // eb 12.8M (h1 @0, h2 @6.4M) | epair 6.4M | f0 6.4M | ptr 400016 |
    // dis 400000 | cntAB 306544 | bsum 1216 | bbase 800 | Bpk 49152
    char* base = (char*)d_ws;
    int2*     eb    = (int2*)base;
    ushort*   h1    = (ushort*)base;
    ushort*   h2    = (ushort*)(base + 6400000);
    unsigned* epair = (unsigned*)(base + 12800000);
    ushort*   f0    = (ushort*)(base + 19200000);
    int*      ptr   = (int*)(base + 25600000);
    float*    dis   = (float*)(base + 26000016);
    unsigned* cntAB = (unsigned*)(base + 26400016);
    unsigned* bsum  = (unsigned*)(base + 26706560);
    unsigned* bbase = (unsigned*)(base + 26707776);
    half8*    Bpk   = (half8*)(base + 26708576);

    // ---- bucket-radix CSR build (no global atomics); cvt + prep ride in pass A ----
    countA_kernel<<<GA + CB + NL, 256, 0, stream>>>(col, cntAB, x, (__half*)f0, W, Bpk);
    scanb_kernel<<<NSC, 256, 0, stream>>>(cntAB, bsum);
    scant_kernel<<<1, 512, 0, stream>>>(bsum);
    scana_kernel<<<NSC, 256, 0, stream>>>(cntAB, bsum, bbase);
    scatterC_kernel<<<GA, 256, 0, stream>>>(row, col, ew, cntAB, eb);
    histD1_kernel<<<NBK, 256, 0, stream>>>(eb, bbase, ptr, dis);
    fillD2_kernel<<<NBK, 256, 0, stream>>>(eb, bbase, ptr, dis, epair);

    // ---- layers: f0 = layer input (fp16, updated in place by fused epilogue) ----
    const int grid = NN / 16;
    for (int l = 0; l < NL; ++l) {
        int lastl = (l == NL - 1);
        gather_kernel<<<grid, 256, 0, stream>>>(f0, h1, ptr, epair);   // k=1
        gather_kernel<<<grid, 256, 0, stream>>>(h1, h2, ptr, epair);   // k=2
        k3ep_kernel<<<grid, 256, 0, stream>>>(f0, h1, h2, f0, out, ptr, epair,
                                              Bpk + (size_t)l * 1024,
                                              b + (size_t)l * DD, lastl);
    }
}

// Round 5
// 308.934 us; speedup vs baseline: 1.2089x; 1.0257x over previous
//
#include <hip/hip_runtime.h>
#include <hip/hip_fp16.h>

#define NN 100000
#define NE 1600000
#define DD 32
#define NL 3
#define NK 3

#define BK 512                       // nodes per bucket
#define NBK ((NN + BK - 1) / BK)     // 196 buckets
#define EA 4096                      // edges per count/scatter block
#define GA ((NE + EA - 1) / EA)      // 391 blocks
#define NCNT (NBK * GA)              // 76636 count-matrix entries
#define NSC ((NCNT + 255) / 256)     // 300 scan blocks
#define CB (NN * DD / 4 / 256)       // 3125 cvt rider blocks (float4)

typedef _Float16 half8 __attribute__((ext_vector_type(8)));
typedef float f32x4 __attribute__((ext_vector_type(4)));

// ---- pass A: per-(block,bucket) edge counts via LDS atomics (no global atomics);
//      cvt (x->fp16) and W-prep ride as extra blocks. ----
__global__ void countA_kernel(const int* __restrict__ col, unsigned* __restrict__ cntAB,
                              const float* __restrict__ x, __half* __restrict__ xh,
                              const float* __restrict__ W, half8* __restrict__ Bpk) {
    __shared__ unsigned hc[NBK];
    int bid = blockIdx.x;
    int t = threadIdx.x;
    if (bid < GA) {
        for (int i = t; i < NBK; i += 256) hc[i] = 0;
        __syncthreads();
        int e0 = bid * EA;
        int e1 = e0 + EA; if (e1 > NE) e1 = NE;
        for (int e = e0 + t; e < e1; e += 256)
            atomicAdd(&hc[((unsigned)col[e]) >> 9], 1u);
        __syncthreads();
        for (int i = t; i < NBK; i += 256)
            cntAB[i * GA + bid] = hc[i];            // bucket-major for the scan
    } else if (bid < GA + CB) {
        int i = (bid - GA) * 256 + t;               // float4 index, 800000 total
        f32x4 v = ((const f32x4*)x)[i];
        __half2 h01 = __floats2half2_rn(v.x, v.y);
        __half2 h23 = __floats2half2_rn(v.z, v.w);
        int2 o;
        o.x = *(int*)&h01; o.y = *(int*)&h23;
        ((int2*)xh)[i] = o;
    } else if (t < 64) {
        // pre-pack B fragments (hi/lo fp16 split, lane layout) for one layer
        int l = bid - GA - CB;
        int m = t & 15, kq = t >> 4;
        for (int c = 0; c < 4; ++c) {
            for (int h = 0; h < 2; ++h) {
                half8 hi, lo;
                for (int j = 0; j < 8; ++j) {
                    float wv = W[(size_t)((l * 4 + c) * DD + kq * 8 + j) * DD + h * 16 + m];
                    _Float16 wh = (_Float16)wv;
                    hi[j] = wh;
                    lo[j] = (_Float16)(wv - (float)wh);
                }
                Bpk[(size_t)(((l * 4 + c) * 2 + h) * 2 + 0) * 64 + t] = hi;
                Bpk[(size_t)(((l * 4 + c) * 2 + h) * 2 + 1) * 64 + t] = lo;
            }
        }
    }
}

// ---- pass B: 3-level exclusive scan of cntAB (76636 entries) ----
__global__ void scanb_kernel(unsigned* __restrict__ a, unsigned* __restrict__ bsum) {
    __shared__ unsigned s[256];
    int t = threadIdx.x;
    int i = blockIdx.x * 256 + t;
    unsigned v = (i < NCNT) ? a[i] : 0u;
    s[t] = v;
    __syncthreads();
    for (int off = 1; off < 256; off <<= 1) {
        unsigned add = (t >= off) ? s[t - off] : 0u;
        __syncthreads();
        s[t] += add;
        __syncthreads();
    }
    if (i < NCNT) a[i] = s[t] - v;                  // block-local exclusive
    if (t == 255) bsum[blockIdx.x] = s[255];
}

__global__ void scant_kernel(unsigned* __restrict__ bsum) {
    __shared__ unsigned s[512];
    int t = threadIdx.x;
    unsigned v = (t < NSC) ? bsum[t] : 0u;
    s[t] = v;
    __syncthreads();
    for (int off = 1; off < 512; off <<= 1) {
        unsigned add = (t >= off) ? s[t - off] : 0u;
        __syncthreads();
        s[t] += add;
        __syncthreads();
    }
    if (t < NSC) bsum[t] = s[t] - v;                // exclusive block offsets
}

__global__ void scana_kernel(unsigned* __restrict__ a, const unsigned* __restrict__ bsum,
                             unsigned* __restrict__ bbase) {
    int i = blockIdx.x * 256 + threadIdx.x;
    if (i < NCNT) {
        unsigned v = a[i] + bsum[i >> 8];
        a[i] = v;
        if (i % GA == 0) bbase[i / GA] = v;         // bucket base = scan at bucket start
    }
    if (i == 0) bbase[NBK] = NE;
}

// ---- pass C: scatter (colLow<<17|row, w) records bucket-contiguously; LDS cursors ----
__global__ void scatterC_kernel(const int* __restrict__ row, const int* __restrict__ col,
                                const float* __restrict__ w,
                                const unsigned* __restrict__ cntAB, int2* __restrict__ eb) {
    __shared__ unsigned cur[NBK];
    int bid = blockIdx.x;
    int t = threadIdx.x;
    for (int i = t; i < NBK; i += 256) cur[i] = cntAB[i * GA + bid];
    __syncthreads();
    int e0 = bid * EA;
    int e1 = e0 + EA; if (e1 > NE) e1 = NE;
    for (int e = e0 + t; e < e1; e += 256) {
        unsigned c = (unsigned)col[e];
        unsigned pos = atomicAdd(&cur[c >> 9], 1u);
        eb[pos] = make_int2((int)(((c & 511u) << 17) | (unsigned)row[e]),
                            __float_as_int(w[e]));
    }
}

// ---- pass D1: per-bucket node histogram (packed count|wsum fixed 2^-17) -> ptr, dis ----
__global__ void histD1_kernel(const int2* __restrict__ eb, const unsigned* __restrict__ bbase,
                              int* __restrict__ ptr, float* __restrict__ dis) {
    __shared__ unsigned h[BK];
    __shared__ unsigned ps[256];
    int b = blockIdx.x;
    int t = threadIdx.x;
    h[t] = 0; h[t + 256] = 0;
    __syncthreads();
    unsigned e0 = bbase[b], e1 = bbase[b + 1];
    for (unsigned e = e0 + t; e < e1; e += 256) {
        int2 E = eb[e];
        unsigned cl = ((unsigned)E.x) >> 17;
        float wv = __int_as_float(E.y);
        atomicAdd(&h[cl], (1u << 24) | (unsigned)(wv * 131072.0f));
    }
    __syncthreads();
    unsigned c0 = h[2 * t] >> 24, c1 = h[2 * t + 1] >> 24;
    unsigned pv = c0 + c1;
    ps[t] = pv;
    __syncthreads();
    for (int off = 1; off < 256; off <<= 1) {
        unsigned add = (t >= off) ? ps[t - off] : 0u;
        __syncthreads();
        ps[t] += add;
        __syncthreads();
    }
    unsigned base = e0 + ps[t] - pv;                // exclusive pair prefix
    int n0 = b * BK + 2 * t;
    if (n0 < NN) {
        ptr[n0] = (int)base;
        float dg = (float)(h[2 * t] & 0xFFFFFFu) * (1.0f / 131072.0f);
        dis[n0] = dg > 0.f ? rsqrtf(dg) : 0.f;
    }
    if (n0 + 1 < NN) {
        ptr[n0 + 1] = (int)(base + c0);
        float dg = (float)(h[2 * t + 1] & 0xFFFFFFu) * (1.0f / 131072.0f);
        dis[n0 + 1] = dg > 0.f ? rsqrtf(dg) : 0.f;
    }
    if (b == 0 && t == 0) ptr[NN] = NE;
}

// ---- pass D2: per-bucket CSR fill via LDS cursors: epair = (fp16(norm)<<17)|row ----
__global__ void fillD2_kernel(const int2* __restrict__ eb, const unsigned* __restrict__ bbase,
                              const int* __restrict__ ptr, const float* __restrict__ dis,
                              unsigned* __restrict__ epair) {
    __shared__ unsigned cur[BK];
    __shared__ float dl[BK];
    int b = blockIdx.x;
    int t = threadIdx.x;
    int n0 = b * BK;
    for (int i = t; i < BK; i += 256) {
        int n = n0 + i;
        cur[i] = (n < NN) ? (unsigned)ptr[n] : 0u;
        dl[i] = (n < NN) ? dis[n] : 0.f;
    }
    __syncthreads();
    unsigned e0 = bbase[b], e1 = bbase[b + 1];
    for (unsigned e = e0 + t; e < e1; e += 256) {
        int2 E = eb[e];
        unsigned cl = ((unsigned)E.x) >> 17;
        unsigned r = ((unsigned)E.x) & 0x1FFFFu;
        float nv = dis[r] * __int_as_float(E.y) * dl[cl];
        unsigned pos = atomicAdd(&cur[cl], 1u);
        unsigned hb = (unsigned)__half_as_ushort(__float2half(nv));
        epair[pos] = (hb << 17) | r;
    }
}

// ---- gather body, 16 lanes/node, ONE 8-deep batched round (covers deg<=32):
//      stream lane (st,c4) owns edges p0+st+4d. All 8 epair loads issue, then all
//      8 independent row loads, then FMAs -> ~128 cachelines in flight per wave
//      and exactly 2 serial load latencies per node for 99.99% of nodes.
//      OOB depths clamp to row p1-1 with weight 0 (dup loads coalesce/L1-hit).
//      Rare tail loop handles deg > 32. ----
#define ACC8(rw, vv)                                                             \
    {                                                                            \
        float2 f0 = __half22float2(*reinterpret_cast<__half2*>(&rw.x));          \
        float2 f1 = __half22float2(*reinterpret_cast<__half2*>(&rw.y));          \
        float2 f2 = __half22float2(*reinterpret_cast<__half2*>(&rw.z));          \
        float2 f3 = __half22float2(*reinterpret_cast<__half2*>(&rw.w));          \
        agg[0] = fmaf(vv, f0.x, agg[0]); agg[1] = fmaf(vv, f0.y, agg[1]);        \
        agg[2] = fmaf(vv, f1.x, agg[2]); agg[3] = fmaf(vv, f1.y, agg[3]);        \
        agg[4] = fmaf(vv, f2.x, agg[4]); agg[5] = fmaf(vv, f2.y, agg[5]);        \
        agg[6] = fmaf(vv, f3.x, agg[6]); agg[7] = fmaf(vv, f3.y, agg[7]);        \
    }

__device__ __forceinline__ void gather_body16(const ushort* __restrict__ hin,
                                              const unsigned* __restrict__ epair,
                                              int p0, int p1, int st, int c4,
                                              float agg[8]) {
    const int4* hin4 = (const int4*)hin;
    int e = p0 + st;
    if (e < p1) {
        unsigned pw[8];
        int4 rw[8];
        #pragma unroll
        for (int d = 0; d < 8; ++d) {
            int ed = e + 4 * d;
            pw[d] = epair[ed < p1 ? ed : p1 - 1];
        }
        #pragma unroll
        for (int d = 0; d < 8; ++d)
            rw[d] = hin4[(size_t)(pw[d] & 0x1FFFFu) * 4 + c4];
        #pragma unroll
        for (int d = 0; d < 8; ++d) {
            float vv = (e + 4 * d < p1)
                ? __half2float(__ushort_as_half((unsigned short)(pw[d] >> 17))) : 0.f;
            ACC8(rw[d], vv);
        }
        // rare tail (deg > 32), stride-4 serial
        for (e = p0 + st + 32; e < p1; e += 4) {
            unsigned p = epair[e];
            int4 r = hin4[(size_t)(p & 0x1FFFFu) * 4 + c4];
            float vv = __half2float(__ushort_as_half((unsigned short)(p >> 17)));
            ACC8(r, vv);
        }
    }
    // reduce over the 4 streams (st) within each 16-lane group
    #pragma unroll
    for (int i = 0; i < 8; ++i) {
        agg[i] += __shfl_xor(agg[i], 4, 16);
        agg[i] += __shfl_xor(agg[i], 8, 16);
    }
}

// --- pure hop: hout[n] = sum norm*hin[src], fp16 in/out. 256 thr = 16 nodes ---
__global__ __launch_bounds__(256) void gather_kernel(
    const ushort* __restrict__ hin, ushort* __restrict__ hout,
    const int* __restrict__ ptr, const unsigned* __restrict__ epair) {
    int tid = threadIdx.x;
    int lane16 = tid & 15;
    int st = lane16 >> 2, c4 = lane16 & 3;
    int n = blockIdx.x * 16 + (tid >> 4);      // NN = 6250*16 exactly
    int p0 = ptr[n], p1 = ptr[n + 1];
    float agg[8] = {0.f, 0.f, 0.f, 0.f, 0.f, 0.f, 0.f, 0.f};
    gather_body16(hin, epair, p0, p1, st, c4, agg);
    if (lane16 < 4) {
        __half2 ha = __floats2half2_rn(agg[0], agg[1]);
        __half2 hb = __floats2half2_rn(agg[2], agg[3]);
        __half2 hc = __floats2half2_rn(agg[4], agg[5]);
        __half2 hd = __floats2half2_rn(agg[6], agg[7]);
        int4 pkv;
        pkv.x = *(int*)&ha; pkv.y = *(int*)&hb;
        pkv.z = *(int*)&hc; pkv.w = *(int*)&hd;
        ((int4*)hout)[(size_t)n * 4 + lane16] = pkv;
    }
}

// --- fused k=3 gather + MFMA epilogue. 256 threads = 16 nodes (16 lanes/node) ---
__global__ __launch_bounds__(256) void k3ep_kernel(
    const ushort* __restrict__ f0, const ushort* __restrict__ h1,
    const ushort* __restrict__ h2,
    ushort* __restrict__ f0out, float* __restrict__ outf,
    const int* __restrict__ ptr, const unsigned* __restrict__ epair,
    const half8* __restrict__ Bp, const float* __restrict__ bias, int last) {
    __shared__ __half ldsH[16 * DD];
    int tid = threadIdx.x;
    int lane16 = tid & 15;
    int st = lane16 >> 2, c4 = lane16 & 3;
    int nloc = tid >> 4;                 // 0..15
    int n0 = blockIdx.x * 16;
    int n = n0 + nloc;                   // NN = 6250*16 exactly, no guard needed
    int p0 = ptr[n], p1 = ptr[n + 1];
    float agg[8] = {0.f, 0.f, 0.f, 0.f, 0.f, 0.f, 0.f, 0.f};
    gather_body16(h2, epair, p0, p1, st, c4, agg);
    if (lane16 < 4) {
        __half2 ha = __floats2half2_rn(agg[0], agg[1]);
        __half2 hb = __floats2half2_rn(agg[2], agg[3]);
        __half2 hc = __floats2half2_rn(agg[4], agg[5]);
        __half2 hd = __floats2half2_rn(agg[6], agg[7]);
        int4 pkv;
        pkv.x = *(int*)&ha; pkv.y = *(int*)&hb;
        pkv.z = *(int*)&hc; pkv.w = *(int*)&hd;
        *(int4*)&ldsH[nloc * DD + lane16 * 8] = pkv;
    }
    __syncthreads();
    if (tid < 64) {
        int m = tid & 15, kq = tid >> 4;
        int ai = (n0 + m) * 4 + kq;
        const half8* A0 = (const half8*)f0;
        const half8* A1 = (const half8*)h1;
        const half8* A2 = (const half8*)h2;
        f32x4 acc0 = {0.f, 0.f, 0.f, 0.f};
        f32x4 acc1 = {0.f, 0.f, 0.f, 0.f};
        half8 a;
        a = A0[ai];
        acc0 = __builtin_amdgcn_mfma_f32_16x16x32_f16(a, Bp[0 * 64 + tid], acc0, 0, 0, 0);
        acc0 = __builtin_amdgcn_mfma_f32_16x16x32_f16(a, Bp[1 * 64 + tid], acc0, 0, 0, 0);
        acc1 = __builtin_amdgcn_mfma_f32_16x16x32_f16(a, Bp[2 * 64 + tid], acc1, 0, 0, 0);
        acc1 = __builtin_amdgcn_mfma_f32_16x16x32_f16(a, Bp[3 * 64 + tid], acc1, 0, 0, 0);
        a = A1[ai];
        acc0 = __builtin_amdgcn_mfma_f32_16x16x32_f16(a, Bp[4 * 64 + tid], acc0, 0, 0, 0);
        acc0 = __builtin_amdgcn_mfma_f32_16x16x32_f16(a, Bp[5 * 64 + tid], acc0, 0, 0, 0);
        acc1 = __builtin_amdgcn_mfma_f32_16x16x32_f16(a, Bp[6 * 64 + tid], acc1, 0, 0, 0);
        acc1 = __builtin_amdgcn_mfma_f32_16x16x32_f16(a, Bp[7 * 64 + tid], acc1, 0, 0, 0);
        a = A2[ai];
        acc0 = __builtin_amdgcn_mfma_f32_16x16x32_f16(a, Bp[8 * 64 + tid], acc0, 0, 0, 0);
        acc0 = __builtin_amdgcn_mfma_f32_16x16x32_f16(a, Bp[9 * 64 + tid], acc0, 0, 0, 0);
        acc1 = __builtin_amdgcn_mfma_f32_16x16x32_f16(a, Bp[10 * 64 + tid], acc1, 0, 0, 0);
        acc1 = __builtin_amdgcn_mfma_f32_16x16x32_f16(a, Bp[11 * 64 + tid], acc1, 0, 0, 0);
        a = *(const half8*)&ldsH[m * DD + kq * 8];
        acc0 = __builtin_amdgcn_mfma_f32_16x16x32_f16(a, Bp[12 * 64 + tid], acc0, 0, 0, 0);
        acc0 = __builtin_amdgcn_mfma_f32_16x16x32_f16(a, Bp[13 * 64 + tid], acc0, 0, 0, 0);
        acc1 = __builtin_amdgcn_mfma_f32_16x16x32_f16(a, Bp[14 * 64 + tid], acc1, 0, 0, 0);
        acc1 = __builtin_amdgcn_mfma_f32_16x16x32_f16(a, Bp[15 * 64 + tid], acc1, 0, 0, 0);
        float b0 = bias[m], b1 = bias[16 + m];
        #pragma unroll
        for (int r = 0; r < 4; ++r) {
            int rowi = n0 + kq * 4 + r;
            float v0 = fmaxf(acc0[r] + b0, 0.f);
            float v1 = fmaxf(acc1[r] + b1, 0.f);
            if (last) {
                outf[rowi * DD + m] = v0;
                outf[rowi * DD + 16 + m] = v1;
            } else {
                ((__half*)f0out)[rowi * DD + m] = __float2half(v0);
                ((__half*)f0out)[rowi * DD + 16 + m] = __float2half(v1);
            }
        }
    }
}

extern "C" void kernel_launch(void* const* d_in, const int* in_sizes, int n_in,
                              void* d_out, int out_size, void* d_ws, size_t ws_size,
                              hipStream_t stream) {
    const float* x  = (const float*)d_in[0];
    const int*   ei = (const int*)d_in[1];
    const float* ew = (const float*)d_in[2];
    const float* W  = (const float*)d_in[3];
    const float* b  = (const float*)d_in[4];
    float* out = (float*)d_out;

    const int* row = ei;        // source
    const int* col = ei + NE;   // target

    // ws layout (bytes), ~26.8 MB. eb is dead after fillD2 -> h1/h2 alias it.
    // eb 12.8M (h1 @0, h2 @6.4M) | epair 6.4M | f0 6.4M | ptr 400016 |
    // dis 400000 | cntAB 306544 | bsum 1216 | bbase 800 | Bpk 49152
    char* base = (char*)d_ws;
    int2*     eb    = (int2*)base;
    ushort*   h1    = (ushort*)base;
    ushort*   h2    = (ushort*)(base + 6400000);
    unsigned* epair = (unsigned*)(base + 12800000);
    ushort*   f0    = (ushort*)(base + 19200000);
    int*      ptr   = (int*)(base + 25600000);
    float*    dis   = (float*)(base + 26000016);
    unsigned* cntAB = (unsigned*)(base + 26400016);
    unsigned* bsum  = (unsigned*)(base + 26706560);
    unsigned* bbase = (unsigned*)(base + 26707776);
    half8*    Bpk   = (half8*)(base + 26708576);

    // ---- bucket-radix CSR build (no global atomics); cvt + prep ride in pass A ----
    countA_kernel<<<GA + CB + NL, 256, 0, stream>>>(col, cntAB, x, (__half*)f0, W, Bpk);
    scanb_kernel<<<NSC, 256, 0, stream>>>(cntAB, bsum);
    scant_kernel<<<1, 512, 0, stream>>>(bsum);
    scana_kernel<<<NSC, 256, 0, stream>>>(cntAB, bsum, bbase);
    scatterC_kernel<<<GA, 256, 0, stream>>>(row, col, ew, cntAB, eb);
    histD1_kernel<<<NBK, 256, 0, stream>>>(eb, bbase, ptr, dis);
    fillD2_kernel<<<NBK, 256, 0, stream>>>(eb, bbase, ptr, dis, epair);

    // ---- layers: f0 = layer input (fp16, updated in place by fused epilogue) ----
    const int grid = NN / 16;
    for (int l = 0; l < NL; ++l) {
        int lastl = (l == NL - 1);
        gather_kernel<<<grid, 256, 0, stream>>>(f0, h1, ptr, epair);   // k=1
        gather_kernel<<<grid, 256, 0, stream>>>(h1, h2, ptr, epair);   // k=2
        k3ep_kernel<<<grid, 256, 0, stream>>>(f0, h1, h2, f0, out, ptr, epair,
                                              Bpk + (size_t)l * 1024,
                                              b + (size_t)l * DD, lastl);
    }
}